// Round 4
// baseline (2939.180 us; speedup 1.0000x reference)
//
#include <hip/hip_runtime.h>
#include <math.h>

#define NB   64      // batch
#define LL   196     // regions
#define AD   512     // image feat dim
#define HD   512     // hidden
#define VD   30000   // vocab
#define TS   20      // steps
#define G4   2048    // 4*H
#define NB5  469     // ceil(30000/64)

typedef __attribute__((ext_vector_type(8))) short short8v;   // 8 bf16 (4 VGPRs)
typedef __attribute__((ext_vector_type(4))) float float4v;   // MFMA acc

__device__ __forceinline__ float fast_tanh(float x) {
    float e = __builtin_exp2f(x * 2.8853900817779268f);   // exp(2x)
    return 1.0f - 2.0f / (e + 1.0f);
}
__device__ __forceinline__ float fast_sigmoid(float x) {
    return 1.0f / (1.0f + __builtin_exp2f(-x * 1.4426950408889634f));
}
__device__ __forceinline__ float fast_exp(float x) {
    return __builtin_exp2f(x * 1.4426950408889634f);
}

// ---- fp32 -> bf16 (RNE) split helpers ----
__device__ __forceinline__ unsigned short bf16_rne(float x) {
    unsigned u = __float_as_uint(x);
    unsigned r = u + 0x7fffu + ((u >> 16) & 1u);
    return (unsigned short)(r >> 16);
}
__device__ __forceinline__ float bf16_f(unsigned short h) {
    return __uint_as_float(((unsigned)h) << 16);
}
__device__ __forceinline__ void split3(float x, unsigned short& a, unsigned short& b,
                                       unsigned short& c) {
    a = bf16_rne(x);
    float r1 = x - bf16_f(a);
    b = bf16_rne(r1);
    float r2 = r1 - bf16_f(b);
    c = bf16_rne(r2);
}

// ---------------- precompute: mean over L, h0/c0, tok init ----------------
__global__ void k_init(const float* __restrict__ hl, const float* __restrict__ Wh0,
                       const float* __restrict__ bh0, const float* __restrict__ Wc0,
                       const float* __restrict__ bc0, float* __restrict__ h_ws,
                       float* __restrict__ c_ws, int* __restrict__ tok_ws) {
    __shared__ float mean_s[AD];
    int n = blockIdx.x, tid = threadIdx.x;
    for (int a = tid; a < AD; a += 256) {
        float acc = 0.f;
        const float* p = hl + ((size_t)n * LL) * AD + a;
        for (int l = 0; l < LL; ++l) acc += p[(size_t)l * AD];
        mean_s[a] = acc / 196.0f;
    }
    __syncthreads();
    for (int hh = tid; hh < HD; hh += 256) {
        float ah = bh0[hh], ac = bc0[hh];
        for (int k = 0; k < AD; ++k) {
            float m = mean_s[k];
            ah = fmaf(m, Wh0[k * HD + hh], ah);
            ac = fmaf(m, Wc0[k * HD + hh], ac);
        }
        h_ws[n * HD + hh] = fast_tanh(ah);
        c_ws[n * HD + hh] = fast_tanh(ac);
    }
    if (tid == 0) tok_ws[n] = 1;  // START
}

// ---------------- precompute: hl_Wa = hl @ Wa  (12544x512 @ 512x512) ----------------
__global__ void k_hlwa(const float* __restrict__ Amat, const float* __restrict__ Bmat,
                       float* __restrict__ Cmat) {
    __shared__ __attribute__((aligned(16))) float xt[64 * 64];  // (k, m) skewed
    int tid = threadIdx.x;
    int lane16 = tid & 15, rowg = tid >> 4;
    int m0 = blockIdx.x * 64, jb = blockIdx.y * 64;
    float acc[4][4] = {};
    for (int ch = 0; ch < 8; ++ch) {
        int kbase = ch * 64;
        __syncthreads();
        for (int it = 0; it < 4; ++it) {
            int k4 = tid & 15;
            int nrow = (tid >> 4) + it * 16;
            float4 v = *(const float4*)&Amat[(size_t)(m0 + nrow) * 512 + kbase + k4 * 4];
            int col = (nrow + k4 * 4) & 63;
            xt[(k4 * 4 + 0) * 64 + col] = v.x;
            xt[(k4 * 4 + 1) * 64 + col] = v.y;
            xt[(k4 * 4 + 2) * 64 + col] = v.z;
            xt[(k4 * 4 + 3) * 64 + col] = v.w;
        }
        __syncthreads();
#pragma unroll 8
        for (int kk = 0; kk < 64; ++kk) {
            float4 w4 = *(const float4*)&Bmat[(size_t)(kbase + kk) * 512 + jb + lane16 * 4];
            float4 h4 = *(const float4*)&xt[kk * 64 + ((rowg * 4 + (kk & ~3)) & 63)];
            float hv[4] = {h4.x, h4.y, h4.z, h4.w};
            float wv[4] = {w4.x, w4.y, w4.z, w4.w};
#pragma unroll
            for (int r = 0; r < 4; ++r)
#pragma unroll
                for (int j = 0; j < 4; ++j) acc[r][j] = fmaf(hv[r], wv[j], acc[r][j]);
        }
    }
    for (int r = 0; r < 4; ++r) {
        float4 o = {acc[r][0], acc[r][1], acc[r][2], acc[r][3]};
        *(float4*)&Cmat[(size_t)(m0 + rowg * 4 + r) * 512 + jb + lane16 * 4] = o;
    }
}

// ---------------- per step: hua_part[s] = h @ Ua[kslice]  (K-split 8) ----------------
__global__ void k_hua(const float* __restrict__ h_ws, const float* __restrict__ Ua,
                      float* __restrict__ hua_part) {
    __shared__ __attribute__((aligned(16))) float xt[64 * 64];
    int tid = threadIdx.x;
    int lane16 = tid & 15, rowg = tid >> 4;
    int s = blockIdx.x & 7, jt = blockIdx.x >> 3;
    int jb = jt * 64, kbase = s * 64;
    float acc[4][4] = {};
    for (int it = 0; it < 4; ++it) {
        int k4 = tid & 15;
        int nrow = (tid >> 4) + it * 16;
        float4 v = *(const float4*)&h_ws[nrow * 512 + kbase + k4 * 4];
        int col = (nrow + k4 * 4) & 63;
        xt[(k4 * 4 + 0) * 64 + col] = v.x;
        xt[(k4 * 4 + 1) * 64 + col] = v.y;
        xt[(k4 * 4 + 2) * 64 + col] = v.z;
        xt[(k4 * 4 + 3) * 64 + col] = v.w;
    }
    __syncthreads();
#pragma unroll 8
    for (int kk = 0; kk < 64; ++kk) {
        float4 w4 = *(const float4*)&Ua[(size_t)(kbase + kk) * 512 + jb + lane16 * 4];
        float4 h4 = *(const float4*)&xt[kk * 64 + ((rowg * 4 + (kk & ~3)) & 63)];
        float hv[4] = {h4.x, h4.y, h4.z, h4.w};
        float wv[4] = {w4.x, w4.y, w4.z, w4.w};
#pragma unroll
        for (int r = 0; r < 4; ++r)
#pragma unroll
            for (int j = 0; j < 4; ++j) acc[r][j] = fmaf(hv[r], wv[j], acc[r][j]);
    }
    float* gp = hua_part + (size_t)s * NB * HD;
    for (int r = 0; r < 4; ++r) {
        float4 o = {acc[r][0], acc[r][1], acc[r][2], acc[r][3]};
        *(float4*)&gp[(size_t)(rowg * 4 + r) * 512 + jb + lane16 * 4] = o;
    }
}

// ---------------- per step: e[n][l] = sum_h tanh(hlWa + hUa + ba) * va ----------------
__global__ void k_att_e(const float* __restrict__ hlwa, const float* __restrict__ hua_part,
                        const float* __restrict__ ba, const float* __restrict__ va,
                        float* __restrict__ e_ws) {
    int n = blockIdx.x >> 2, q = blockIdx.x & 3;
    int tid = threadIdx.x;
    int wave = tid >> 6, lane = tid & 63;
    float4 ua_a = *(const float4*)&ba[lane * 4];
    float4 ua_b = *(const float4*)&ba[256 + lane * 4];
    for (int s = 0; s < 8; ++s) {
        const float* p = hua_part + (size_t)s * NB * HD + n * HD;
        float4 pa = *(const float4*)&p[lane * 4];
        float4 pb = *(const float4*)&p[256 + lane * 4];
        ua_a.x += pa.x; ua_a.y += pa.y; ua_a.z += pa.z; ua_a.w += pa.w;
        ua_b.x += pb.x; ua_b.y += pb.y; ua_b.z += pb.z; ua_b.w += pb.w;
    }
    float4 va_a = *(const float4*)&va[lane * 4];
    float4 va_b = *(const float4*)&va[256 + lane * 4];
    for (int ll = wave; ll < 49; ll += 4) {
        int l = q * 49 + ll;
        const float* base = hlwa + ((size_t)n * LL + l) * HD;
        float4 xa = *(const float4*)&base[lane * 4];
        float4 xb = *(const float4*)&base[256 + lane * 4];
        float s = 0.f;
        s = fmaf(fast_tanh(xa.x + ua_a.x), va_a.x, s);
        s = fmaf(fast_tanh(xa.y + ua_a.y), va_a.y, s);
        s = fmaf(fast_tanh(xa.z + ua_a.z), va_a.z, s);
        s = fmaf(fast_tanh(xa.w + ua_a.w), va_a.w, s);
        s = fmaf(fast_tanh(xb.x + ua_b.x), va_b.x, s);
        s = fmaf(fast_tanh(xb.y + ua_b.y), va_b.y, s);
        s = fmaf(fast_tanh(xb.z + ua_b.z), va_b.z, s);
        s = fmaf(fast_tanh(xb.w + ua_b.w), va_b.w, s);
        for (int m = 1; m < 64; m <<= 1) s += __shfl_xor(s, m, 64);
        if (lane == 0) e_ws[n * LL + l] = s;
    }
}

// ---------------- per step: softmax over L, beta gate, z = (alpha @ hl) * beta ----------------
__global__ void k_soft_z(const float* __restrict__ e_ws, const float* __restrict__ hl,
                         const float* __restrict__ h_ws, const float* __restrict__ Wb,
                         const float* __restrict__ bb, float* __restrict__ z_ws) {
    __shared__ float red[256];
    __shared__ float alpha[256];
    __shared__ float zs[512];
    __shared__ float beta_s;
    int n = blockIdx.x, tid = threadIdx.x;
    float ev = (tid < LL) ? e_ws[n * LL + tid] : -INFINITY;
    red[tid] = ev;
    __syncthreads();
    for (int s = 128; s > 0; s >>= 1) {
        if (tid < s) red[tid] = fmaxf(red[tid], red[tid + s]);
        __syncthreads();
    }
    float m = red[0];
    __syncthreads();
    float a = (tid < LL) ? fast_exp(ev - m) : 0.f;
    red[tid] = a;
    __syncthreads();
    for (int s = 128; s > 0; s >>= 1) {
        if (tid < s) red[tid] += red[tid + s];
        __syncthreads();
    }
    float sum = red[0];
    alpha[tid] = a / sum;
    __syncthreads();
    float bp = h_ws[n * HD + tid] * Wb[tid] + h_ws[n * HD + 256 + tid] * Wb[256 + tid];
    red[tid] = bp;
    __syncthreads();
    for (int s = 128; s > 0; s >>= 1) {
        if (tid < s) red[tid] += red[tid + s];
        __syncthreads();
    }
    if (tid == 0) beta_s = fast_sigmoid(red[0] + bb[0]);
    int lq = tid >> 7, ai = tid & 127;
    const float* base = hl + ((size_t)n * LL) * AD + ai * 4;
    float4 acc4 = {0.f, 0.f, 0.f, 0.f};
    int l0 = lq * 98, l1 = l0 + 98;
    for (int l = l0; l < l1; ++l) {
        float al = alpha[l];
        float4 v = *(const float4*)&base[(size_t)l * AD];
        acc4.x = fmaf(al, v.x, acc4.x);
        acc4.y = fmaf(al, v.y, acc4.y);
        acc4.z = fmaf(al, v.z, acc4.z);
        acc4.w = fmaf(al, v.w, acc4.w);
    }
    if (lq == 1) *(float4*)&zs[ai * 4] = acc4;
    __syncthreads();
    if (lq == 0) {
        float4 o = *(const float4*)&zs[ai * 4];
        float b = beta_s;
        o.x = (o.x + acc4.x) * b;
        o.y = (o.y + acc4.y) * b;
        o.z = (o.z + acc4.z) * b;
        o.w = (o.w + acc4.w) * b;
        *(float4*)&z_ws[n * AD + ai * 4] = o;
    }
}

// ---------------- per step: gates partial GEMM  X[64x1536] @ W[1536x2048], K split 8 ----------------
__global__ void k_gates(const float* __restrict__ z_ws, const float* __restrict__ emb,
                        const int* __restrict__ tok_ws, const float* __restrict__ h_ws,
                        const float* __restrict__ Wx, const float* __restrict__ Wh,
                        float* __restrict__ gates_part) {
    __shared__ __attribute__((aligned(16))) float xt[64 * 64];
    int tid = threadIdx.x;
    int lane16 = tid & 15, rowg = tid >> 4;
    int s = blockIdx.x & 7, jt = blockIdx.x >> 3;
    int jb = jt * 64;
    float acc[4][4] = {};
    for (int ch = 0; ch < 3; ++ch) {
        int kbase = s * 192 + ch * 64;
        __syncthreads();
        for (int it = 0; it < 4; ++it) {
            int nrow = (tid >> 4) + it * 16;
            int k4 = tid & 15;
            int gk = kbase + k4 * 4;
            const float* src;
            if (gk < 512)       src = &z_ws[nrow * 512 + gk];
            else if (gk < 1024) src = &emb[(size_t)tok_ws[nrow] * 512 + (gk - 512)];
            else                src = &h_ws[nrow * 512 + (gk - 1024)];
            float4 v = *(const float4*)src;
            int col = (nrow + k4 * 4) & 63;
            xt[(k4 * 4 + 0) * 64 + col] = v.x;
            xt[(k4 * 4 + 1) * 64 + col] = v.y;
            xt[(k4 * 4 + 2) * 64 + col] = v.z;
            xt[(k4 * 4 + 3) * 64 + col] = v.w;
        }
        __syncthreads();
#pragma unroll 8
        for (int kk = 0; kk < 64; ++kk) {
            int gk = kbase + kk;
            const float* wrow = (gk < 1024) ? &Wx[(size_t)gk * G4] : &Wh[(size_t)(gk - 1024) * G4];
            float4 w4 = *(const float4*)&wrow[jb + lane16 * 4];
            float4 h4 = *(const float4*)&xt[kk * 64 + ((rowg * 4 + (kk & ~3)) & 63)];
            float hv[4] = {h4.x, h4.y, h4.z, h4.w};
            float wv[4] = {w4.x, w4.y, w4.z, w4.w};
#pragma unroll
            for (int r = 0; r < 4; ++r)
#pragma unroll
                for (int j = 0; j < 4; ++j) acc[r][j] = fmaf(hv[r], wv[j], acc[r][j]);
        }
    }
    float* gp = gates_part + (size_t)s * NB * G4;
    for (int r = 0; r < 4; ++r) {
        float4 o = {acc[r][0], acc[r][1], acc[r][2], acc[r][3]};
        *(float4*)&gp[(size_t)(rowg * 4 + r) * G4 + jb + lane16 * 4] = o;
    }
}

// ---------------- per step: reduce gate partials + LSTM cell + h bf16x3 split ----------------
__global__ void k_lstm(const float* __restrict__ gates_part, const float* __restrict__ b_lstm,
                       float* __restrict__ h_ws, float* __restrict__ c_ws,
                       unsigned short* __restrict__ h_hi, unsigned short* __restrict__ h_mid,
                       unsigned short* __restrict__ h_lo) {
    int idx = blockIdx.x * 256 + threadIdx.x;  // 0..32767 = n*512 + hh
    int n = idx >> 9, hh = idx & 511;
    float ig = b_lstm[hh], fg = b_lstm[512 + hh], gg = b_lstm[1024 + hh], og = b_lstm[1536 + hh];
    for (int s = 0; s < 8; ++s) {
        const float* gp = gates_part + (size_t)s * NB * G4 + (size_t)n * G4;
        ig += gp[hh]; fg += gp[512 + hh]; gg += gp[1024 + hh]; og += gp[1536 + hh];
    }
    float c = c_ws[idx];
    float cn = fast_sigmoid(fg) * c + fast_sigmoid(ig) * fast_tanh(gg);
    float hn = fast_sigmoid(og) * fast_tanh(cn);
    c_ws[idx] = cn;
    h_ws[idx] = hn;
    unsigned short a, b, cc;
    split3(hn, a, b, cc);
    h_hi[idx] = a; h_mid[idx] = b; h_lo[idx] = cc;   // [m][k] row-major, A-frag friendly
}

// ---------------- per step: logits = h @ Wout + bout via bf16x3 MFMA ----------------
// Block: 64 vocab cols x 64 batch rows. 4 waves K-split (each K=128).
// A-frag (16x16x32 bf16): A[m=lane&15][k=quad*8+j] -> contiguous 16B from h_{hi,mid,lo}.
// B-frag: B[k=quad*8+j][n=lane&15] -> 8 strided fp32 loads from Wout, split to bf16x3 in VALU.
// C/D: col=lane&15, row=quad*4+reg. Cross-wave K-reduce in LDS, then bias+argmax.
__global__ void k_logits(const unsigned short* __restrict__ h_hi,
                         const unsigned short* __restrict__ h_mid,
                         const unsigned short* __restrict__ h_lo,
                         const float* __restrict__ Wout, const float* __restrict__ bout,
                         float* __restrict__ pval, int* __restrict__ pidx) {
    __shared__ __attribute__((aligned(16))) float part[4 * 64 * 64];  // 64 KB
    int tid = threadIdx.x;
    int w = tid >> 6, lane = tid & 63;
    int l15 = lane & 15, quad = lane >> 4;
    int jb = blockIdx.x * 64;
    if (jb > VD - 64) jb = VD - 64;   // clamp last tile; overlap recompute is harmless
    int kb = w * 128;

    float4v acc[4][4] = {{{0.f}}};    // [m-tile][n-tile]
    for (int c = 0; c < 4; ++c) {
        int k0 = kb + c * 32;
        short8v afrag[4][3];
#pragma unroll
        for (int mt = 0; mt < 4; ++mt) {
            size_t off = (size_t)(mt * 16 + l15) * 512 + k0 + quad * 8;
            afrag[mt][0] = *(const short8v*)&h_hi[off];
            afrag[mt][1] = *(const short8v*)&h_mid[off];
            afrag[mt][2] = *(const short8v*)&h_lo[off];
        }
#pragma unroll
        for (int nt = 0; nt < 4; ++nt) {
            const float* wp = &Wout[(size_t)(k0 + quad * 8) * VD + jb + nt * 16 + l15];
            float wv[8];
#pragma unroll
            for (int j = 0; j < 8; ++j) wv[j] = wp[(size_t)j * VD];
            short8v bhi, bmid, blo;
#pragma unroll
            for (int j = 0; j < 8; ++j) {
                unsigned short x, y, z;
                split3(wv[j], x, y, z);
                bhi[j] = (short)x; bmid[j] = (short)y; blo[j] = (short)z;
            }
#pragma unroll
            for (int mt = 0; mt < 4; ++mt) {
                float4v a = acc[mt][nt];
                a = __builtin_amdgcn_mfma_f32_16x16x32_bf16(afrag[mt][2], bhi,  a, 0, 0, 0);
                a = __builtin_amdgcn_mfma_f32_16x16x32_bf16(afrag[mt][0], blo,  a, 0, 0, 0);
                a = __builtin_amdgcn_mfma_f32_16x16x32_bf16(afrag[mt][1], bmid, a, 0, 0, 0);
                a = __builtin_amdgcn_mfma_f32_16x16x32_bf16(afrag[mt][1], bhi,  a, 0, 0, 0);
                a = __builtin_amdgcn_mfma_f32_16x16x32_bf16(afrag[mt][0], bmid, a, 0, 0, 0);
                a = __builtin_amdgcn_mfma_f32_16x16x32_bf16(afrag[mt][0], bhi,  a, 0, 0, 0);
                acc[mt][nt] = a;
            }
        }
    }
    // write K-partials: part[w][m][n]
    float* myp = part + w * 4096;
#pragma unroll
    for (int mt = 0; mt < 4; ++mt)
#pragma unroll
        for (int nt = 0; nt < 4; ++nt)
#pragma unroll
            for (int r = 0; r < 4; ++r)
                myp[(mt * 16 + quad * 4 + r) * 64 + nt * 16 + l15] = acc[mt][nt][r];
    __syncthreads();
    // reduce 4 partials + bias + per-row argmax; thread -> (row = tid>>2, 16 cols)
    int row = tid >> 2, cg = (tid & 3) << 4;
    const float* p0 = part + row * 64 + cg;
    float best = -INFINITY;
    int bi = 0x7fffffff;
#pragma unroll
    for (int c4 = 0; c4 < 16; c4 += 4) {
        float4 s0 = *(const float4*)&p0[c4];
        float4 s1 = *(const float4*)&p0[4096 + c4];
        float4 s2 = *(const float4*)&p0[8192 + c4];
        float4 s3 = *(const float4*)&p0[12288 + c4];
        float4 b4 = *(const float4*)&bout[jb + cg + c4];
        float v0 = s0.x + s1.x + s2.x + s3.x + b4.x;
        float v1 = s0.y + s1.y + s2.y + s3.y + b4.y;
        float v2 = s0.z + s1.z + s2.z + s3.z + b4.z;
        float v3 = s0.w + s1.w + s2.w + s3.w + b4.w;
        int base = jb + cg + c4;
        if (v0 > best) { best = v0; bi = base; }
        if (v1 > best) { best = v1; bi = base + 1; }
        if (v2 > best) { best = v2; bi = base + 2; }
        if (v3 > best) { best = v3; bi = base + 3; }
    }
    for (int m = 1; m < 4; m <<= 1) {
        float ov = __shfl_xor(best, m, 64);
        int oi = __shfl_xor(bi, m, 64);
        if (ov > best || (ov == best && oi < bi)) { best = ov; bi = oi; }
    }
    if ((tid & 3) == 0) {
        pval[row * NB5 + blockIdx.x] = best;
        pidx[row * NB5 + blockIdx.x] = bi;
    }
}

// ---------------- per step: final argmax over block partials -> token ----------------
__global__ void k_argmax(const float* __restrict__ pval, const int* __restrict__ pidx,
                         int* __restrict__ tok_ws, int* __restrict__ out, int t) {
    int n = blockIdx.x, lane = threadIdx.x;
    float best = -INFINITY; int bi = 0x7fffffff;
    for (int b = lane; b < NB5; b += 64) {
        float v = pval[n * NB5 + b];
        int id = pidx[n * NB5 + b];
        if (v > best || (v == best && id < bi)) { best = v; bi = id; }
    }
    for (int m = 1; m < 64; m <<= 1) {
        float ov = __shfl_xor(best, m, 64);
        int oi = __shfl_xor(bi, m, 64);
        if (ov > best || (ov == best && oi < bi)) { best = ov; bi = oi; }
    }
    if (lane == 0) { tok_ws[n] = bi; out[n * TS + t] = bi; }
}

extern "C" void kernel_launch(void* const* d_in, const int* in_sizes, int n_in,
                              void* d_out, int out_size, void* d_ws, size_t ws_size,
                              hipStream_t stream) {
    const float* hl     = (const float*)d_in[0];
    const float* emb    = (const float*)d_in[1];
    const float* Wh0    = (const float*)d_in[2];
    const float* bh0    = (const float*)d_in[3];
    const float* Wc0    = (const float*)d_in[4];
    const float* bc0    = (const float*)d_in[5];
    const float* Wa     = (const float*)d_in[6];
    const float* Ua     = (const float*)d_in[7];
    const float* ba     = (const float*)d_in[8];
    const float* va     = (const float*)d_in[9];
    const float* Wb     = (const float*)d_in[10];
    const float* bb     = (const float*)d_in[11];
    const float* Wx     = (const float*)d_in[12];
    const float* Wh     = (const float*)d_in[13];
    const float* b_lstm = (const float*)d_in[14];
    const float* Wout   = (const float*)d_in[15];
    const float* bout   = (const float*)d_in[16];

    float* ws         = (float*)d_ws;
    float* hlwa       = ws;                          // 6422528
    float* h_ws       = ws + 6422528;                // 32768
    float* c_ws       = h_ws + 32768;                // 32768
    float* z_ws       = c_ws + 32768;                // 32768
    float* e_ws       = z_ws + 32768;                // 12544
    int*   tok_ws     = (int*)(e_ws + 12544);        // 64
    float* hua_part   = e_ws + 12544 + 64;           // 8*64*512 = 262144
    float* gates_part = hua_part + 262144;           // 8*64*2048 = 1048576
    float* pval       = gates_part + 1048576;        // 64*469 = 30016
    int*   pidx       = (int*)(pval + 30016);        // 30016
    unsigned short* h_hi  = (unsigned short*)(pidx + 30016);  // 32768 ushort (16B-aligned)
    unsigned short* h_mid = h_hi + 32768;
    unsigned short* h_lo  = h_mid + 32768;
    int*   out        = (int*)d_out;

    k_init<<<64, 256, 0, stream>>>(hl, Wh0, bh0, Wc0, bc0, h_ws, c_ws, tok_ws);
    k_hlwa<<<dim3(196, 8), 256, 0, stream>>>(hl, Wa, hlwa);
    for (int t = 0; t < TS; ++t) {
        k_hua<<<64, 256, 0, stream>>>(h_ws, Ua, hua_part);
        k_att_e<<<256, 256, 0, stream>>>(hlwa, hua_part, ba, va, e_ws);
        k_soft_z<<<64, 256, 0, stream>>>(e_ws, hl, h_ws, Wb, bb, z_ws);
        k_gates<<<256, 256, 0, stream>>>(z_ws, emb, tok_ws, h_ws, Wx, Wh, gates_part);
        k_lstm<<<128, 256, 0, stream>>>(gates_part, b_lstm, h_ws, c_ws, h_hi, h_mid, h_lo);
        k_logits<<<NB5, 256, 0, stream>>>(h_hi, h_mid, h_lo, Wout, bout, pval, pidx);
        k_argmax<<<64, 64, 0, stream>>>(pval, pidx, tok_ws, out, t);
    }
}

// Round 5
// 2770.256 us; speedup vs baseline: 1.0610x; 1.0610x over previous
//
#include <hip/hip_runtime.h>
#include <math.h>

#define NB   64      // batch
#define LL   196     // regions
#define AD   512     // image feat dim
#define HD   512     // hidden
#define VD   30000   // vocab
#define VDP  30016   // padded vocab (469*64)
#define TS   20      // steps
#define G4   2048    // 4*H
#define NB5  469     // ceil(30000/64)

typedef __attribute__((ext_vector_type(8))) short short8v;   // 8 bf16 (4 VGPRs)
typedef __attribute__((ext_vector_type(4))) float float4v;   // MFMA acc

__device__ __forceinline__ float fast_tanh(float x) {
    float e = __builtin_exp2f(x * 2.8853900817779268f);   // exp(2x)
    return 1.0f - 2.0f / (e + 1.0f);
}
__device__ __forceinline__ float fast_sigmoid(float x) {
    return 1.0f / (1.0f + __builtin_exp2f(-x * 1.4426950408889634f));
}
__device__ __forceinline__ float fast_exp(float x) {
    return __builtin_exp2f(x * 1.4426950408889634f);
}

// ---- fp32 -> bf16 (RNE) split helpers ----
__device__ __forceinline__ unsigned short bf16_rne(float x) {
    unsigned u = __float_as_uint(x);
    unsigned r = u + 0x7fffu + ((u >> 16) & 1u);
    return (unsigned short)(r >> 16);
}
__device__ __forceinline__ float bf16_f(unsigned short h) {
    return __uint_as_float(((unsigned)h) << 16);
}
__device__ __forceinline__ void split3(float x, unsigned short& a, unsigned short& b,
                                       unsigned short& c) {
    a = bf16_rne(x);
    float r1 = x - bf16_f(a);
    b = bf16_rne(r1);
    float r2 = r1 - bf16_f(b);
    c = bf16_rne(r2);
}

// ---------------- precompute: mean over L, h0/c0, tok init ----------------
__global__ void k_init(const float* __restrict__ hl, const float* __restrict__ Wh0,
                       const float* __restrict__ bh0, const float* __restrict__ Wc0,
                       const float* __restrict__ bc0, float* __restrict__ h_ws,
                       float* __restrict__ c_ws, int* __restrict__ tok_ws) {
    __shared__ float mean_s[AD];
    int n = blockIdx.x, tid = threadIdx.x;
    for (int a = tid; a < AD; a += 256) {
        float acc = 0.f;
        const float* p = hl + ((size_t)n * LL) * AD + a;
        for (int l = 0; l < LL; ++l) acc += p[(size_t)l * AD];
        mean_s[a] = acc / 196.0f;
    }
    __syncthreads();
    for (int hh = tid; hh < HD; hh += 256) {
        float ah = bh0[hh], ac = bc0[hh];
        for (int k = 0; k < AD; ++k) {
            float m = mean_s[k];
            ah = fmaf(m, Wh0[k * HD + hh], ah);
            ac = fmaf(m, Wc0[k * HD + hh], ac);
        }
        h_ws[n * HD + hh] = fast_tanh(ah);
        c_ws[n * HD + hh] = fast_tanh(ac);
    }
    if (tid == 0) tok_ws[n] = 1;  // START
}

// ---------------- precompute: split+transpose Wout -> wt_{hi,mid,lo}[n][k] bf16 ----------------
__global__ void k_wsplit(const float* __restrict__ Wout, unsigned short* __restrict__ wt_hi,
                         unsigned short* __restrict__ wt_mid, unsigned short* __restrict__ wt_lo) {
    __shared__ float tile[64 * 65];   // [k_local][n_local] padded
    int tid = threadIdx.x;
    int nt = blockIdx.x, kt = blockIdx.y;   // 469 n-tiles, 8 k-tiles
    int kr = tid >> 4, nq = tid & 15;
    for (int p = 0; p < 4; ++p) {
        int k = p * 16 + kr;
        int kg = kt * 64 + k;
        int n0 = nt * 64 + nq * 4;
        float4 v;
        if (n0 + 4 <= VD) {
            v = *(const float4*)&Wout[(size_t)kg * VD + n0];
        } else {   // only last n-tile's tail (rows unread by k_logits; clamp for bounds)
            v.x = Wout[(size_t)kg * VD + (n0 + 0 < VD ? n0 + 0 : VD - 1)];
            v.y = Wout[(size_t)kg * VD + (n0 + 1 < VD ? n0 + 1 : VD - 1)];
            v.z = Wout[(size_t)kg * VD + (n0 + 2 < VD ? n0 + 2 : VD - 1)];
            v.w = Wout[(size_t)kg * VD + (n0 + 3 < VD ? n0 + 3 : VD - 1)];
        }
        tile[k * 65 + nq * 4 + 0] = v.x;
        tile[k * 65 + nq * 4 + 1] = v.y;
        tile[k * 65 + nq * 4 + 2] = v.z;
        tile[k * 65 + nq * 4 + 3] = v.w;
    }
    __syncthreads();
    for (int p = 0; p < 2; ++p) {
        int n_l = p * 32 + (tid >> 3);
        int kc = tid & 7;
        short8v hi8, mid8, lo8;
#pragma unroll
        for (int j = 0; j < 8; ++j) {
            float x = tile[(kc * 8 + j) * 65 + n_l];
            unsigned short a, b, c;
            split3(x, a, b, c);
            hi8[j] = (short)a; mid8[j] = (short)b; lo8[j] = (short)c;
        }
        size_t off = (size_t)(nt * 64 + n_l) * 512 + kt * 64 + kc * 8;
        *(short8v*)&wt_hi[off] = hi8;
        *(short8v*)&wt_mid[off] = mid8;
        *(short8v*)&wt_lo[off] = lo8;
    }
}

// ---------------- precompute: hl_Wa = hl @ Wa  (12544x512 @ 512x512) ----------------
__global__ void k_hlwa(const float* __restrict__ Amat, const float* __restrict__ Bmat,
                       float* __restrict__ Cmat) {
    __shared__ __attribute__((aligned(16))) float xt[64 * 64];  // (k, m) skewed
    int tid = threadIdx.x;
    int lane16 = tid & 15, rowg = tid >> 4;
    int m0 = blockIdx.x * 64, jb = blockIdx.y * 64;
    float acc[4][4] = {};
    for (int ch = 0; ch < 8; ++ch) {
        int kbase = ch * 64;
        __syncthreads();
        for (int it = 0; it < 4; ++it) {
            int k4 = tid & 15;
            int nrow = (tid >> 4) + it * 16;
            float4 v = *(const float4*)&Amat[(size_t)(m0 + nrow) * 512 + kbase + k4 * 4];
            int col = (nrow + k4 * 4) & 63;
            xt[(k4 * 4 + 0) * 64 + col] = v.x;
            xt[(k4 * 4 + 1) * 64 + col] = v.y;
            xt[(k4 * 4 + 2) * 64 + col] = v.z;
            xt[(k4 * 4 + 3) * 64 + col] = v.w;
        }
        __syncthreads();
#pragma unroll 8
        for (int kk = 0; kk < 64; ++kk) {
            float4 w4 = *(const float4*)&Bmat[(size_t)(kbase + kk) * 512 + jb + lane16 * 4];
            float4 h4 = *(const float4*)&xt[kk * 64 + ((rowg * 4 + (kk & ~3)) & 63)];
            float hv[4] = {h4.x, h4.y, h4.z, h4.w};
            float wv[4] = {w4.x, w4.y, w4.z, w4.w};
#pragma unroll
            for (int r = 0; r < 4; ++r)
#pragma unroll
                for (int j = 0; j < 4; ++j) acc[r][j] = fmaf(hv[r], wv[j], acc[r][j]);
        }
    }
    for (int r = 0; r < 4; ++r) {
        float4 o = {acc[r][0], acc[r][1], acc[r][2], acc[r][3]};
        *(float4*)&Cmat[(size_t)(m0 + rowg * 4 + r) * 512 + jb + lane16 * 4] = o;
    }
}

// ---------------- per step: hua_part[s] = h @ Ua[kslice]  (K-split 8) ----------------
__global__ void k_hua(const float* __restrict__ h_ws, const float* __restrict__ Ua,
                      float* __restrict__ hua_part) {
    __shared__ __attribute__((aligned(16))) float xt[64 * 64];
    int tid = threadIdx.x;
    int lane16 = tid & 15, rowg = tid >> 4;
    int s = blockIdx.x & 7, jt = blockIdx.x >> 3;
    int jb = jt * 64, kbase = s * 64;
    float acc[4][4] = {};
    for (int it = 0; it < 4; ++it) {
        int k4 = tid & 15;
        int nrow = (tid >> 4) + it * 16;
        float4 v = *(const float4*)&h_ws[nrow * 512 + kbase + k4 * 4];
        int col = (nrow + k4 * 4) & 63;
        xt[(k4 * 4 + 0) * 64 + col] = v.x;
        xt[(k4 * 4 + 1) * 64 + col] = v.y;
        xt[(k4 * 4 + 2) * 64 + col] = v.z;
        xt[(k4 * 4 + 3) * 64 + col] = v.w;
    }
    __syncthreads();
#pragma unroll 8
    for (int kk = 0; kk < 64; ++kk) {
        float4 w4 = *(const float4*)&Ua[(size_t)(kbase + kk) * 512 + jb + lane16 * 4];
        float4 h4 = *(const float4*)&xt[kk * 64 + ((rowg * 4 + (kk & ~3)) & 63)];
        float hv[4] = {h4.x, h4.y, h4.z, h4.w};
        float wv[4] = {w4.x, w4.y, w4.z, w4.w};
#pragma unroll
        for (int r = 0; r < 4; ++r)
#pragma unroll
            for (int j = 0; j < 4; ++j) acc[r][j] = fmaf(hv[r], wv[j], acc[r][j]);
    }
    float* gp = hua_part + (size_t)s * NB * HD;
    for (int r = 0; r < 4; ++r) {
        float4 o = {acc[r][0], acc[r][1], acc[r][2], acc[r][3]};
        *(float4*)&gp[(size_t)(rowg * 4 + r) * 512 + jb + lane16 * 4] = o;
    }
}

// ---------------- per step: e[n][l] = sum_h tanh(hlWa + hUa + ba) * va ----------------
__global__ void k_att_e(const float* __restrict__ hlwa, const float* __restrict__ hua_part,
                        const float* __restrict__ ba, const float* __restrict__ va,
                        float* __restrict__ e_ws) {
    int n = blockIdx.x >> 2, q = blockIdx.x & 3;
    int tid = threadIdx.x;
    int wave = tid >> 6, lane = tid & 63;
    float4 ua_a = *(const float4*)&ba[lane * 4];
    float4 ua_b = *(const float4*)&ba[256 + lane * 4];
    for (int s = 0; s < 8; ++s) {
        const float* p = hua_part + (size_t)s * NB * HD + n * HD;
        float4 pa = *(const float4*)&p[lane * 4];
        float4 pb = *(const float4*)&p[256 + lane * 4];
        ua_a.x += pa.x; ua_a.y += pa.y; ua_a.z += pa.z; ua_a.w += pa.w;
        ua_b.x += pb.x; ua_b.y += pb.y; ua_b.z += pb.z; ua_b.w += pb.w;
    }
    float4 va_a = *(const float4*)&va[lane * 4];
    float4 va_b = *(const float4*)&va[256 + lane * 4];
    for (int ll = wave; ll < 49; ll += 4) {
        int l = q * 49 + ll;
        const float* base = hlwa + ((size_t)n * LL + l) * HD;
        float4 xa = *(const float4*)&base[lane * 4];
        float4 xb = *(const float4*)&base[256 + lane * 4];
        float s = 0.f;
        s = fmaf(fast_tanh(xa.x + ua_a.x), va_a.x, s);
        s = fmaf(fast_tanh(xa.y + ua_a.y), va_a.y, s);
        s = fmaf(fast_tanh(xa.z + ua_a.z), va_a.z, s);
        s = fmaf(fast_tanh(xa.w + ua_a.w), va_a.w, s);
        s = fmaf(fast_tanh(xb.x + ua_b.x), va_b.x, s);
        s = fmaf(fast_tanh(xb.y + ua_b.y), va_b.y, s);
        s = fmaf(fast_tanh(xb.z + ua_b.z), va_b.z, s);
        s = fmaf(fast_tanh(xb.w + ua_b.w), va_b.w, s);
        for (int m = 1; m < 64; m <<= 1) s += __shfl_xor(s, m, 64);
        if (lane == 0) e_ws[n * LL + l] = s;
    }
}

// ---------------- per step: softmax over L, beta gate, z = (alpha @ hl) * beta ----------------
// grid 256: n = blk>>2, a-chunk = blk&3 (128 cols each); softmax/beta duplicated per block
__global__ void k_soft_z(const float* __restrict__ e_ws, const float* __restrict__ hl,
                         const float* __restrict__ h_ws, const float* __restrict__ Wb,
                         const float* __restrict__ bb, float* __restrict__ z_ws) {
    __shared__ float red[256];
    __shared__ float alpha[200];
    __shared__ float4 partz[8][32];
    __shared__ float beta_s;
    int n = blockIdx.x >> 2, ac = blockIdx.x & 3;
    int tid = threadIdx.x;
    float ev = (tid < LL) ? e_ws[n * LL + tid] : -INFINITY;
    red[tid] = ev;
    __syncthreads();
    for (int s = 128; s > 0; s >>= 1) {
        if (tid < s) red[tid] = fmaxf(red[tid], red[tid + s]);
        __syncthreads();
    }
    float m = red[0];
    __syncthreads();
    float a = (tid < LL) ? fast_exp(ev - m) : 0.f;
    red[tid] = a;
    __syncthreads();
    for (int s = 128; s > 0; s >>= 1) {
        if (tid < s) red[tid] += red[tid + s];
        __syncthreads();
    }
    float sum = red[0];
    if (tid < LL) alpha[tid] = a / sum;
    __syncthreads();
    float bp = h_ws[n * HD + tid] * Wb[tid] + h_ws[n * HD + 256 + tid] * Wb[256 + tid];
    red[tid] = bp;
    __syncthreads();
    for (int s = 128; s > 0; s >>= 1) {
        if (tid < s) red[tid] += red[tid + s];
        __syncthreads();
    }
    if (tid == 0) beta_s = fast_sigmoid(red[0] + bb[0]);
    // z over this block's 128 a-cols: 32 quads x 8 l-groups
    int aq = tid & 31, lg = tid >> 5;
    const float* base = hl + ((size_t)n * LL) * AD + ac * 128 + aq * 4;
    float4 acc4 = {0.f, 0.f, 0.f, 0.f};
    for (int l = lg; l < LL; l += 8) {
        float al = alpha[l];
        float4 v = *(const float4*)&base[(size_t)l * AD];
        acc4.x = fmaf(al, v.x, acc4.x);
        acc4.y = fmaf(al, v.y, acc4.y);
        acc4.z = fmaf(al, v.z, acc4.z);
        acc4.w = fmaf(al, v.w, acc4.w);
    }
    partz[lg][aq] = acc4;
    __syncthreads();
    if (tid < 32) {
        float4 o = partz[0][tid];
        for (int g = 1; g < 8; ++g) {
            float4 p = partz[g][tid];
            o.x += p.x; o.y += p.y; o.z += p.z; o.w += p.w;
        }
        float b = beta_s;
        o.x *= b; o.y *= b; o.z *= b; o.w *= b;
        *(float4*)&z_ws[n * AD + ac * 128 + tid * 4] = o;
    }
}

// ---------------- per step: gates partial GEMM  X[64x1536] @ W[1536x2048], K split 8 ----------------
__global__ void k_gates(const float* __restrict__ z_ws, const float* __restrict__ emb,
                        const int* __restrict__ tok_ws, const float* __restrict__ h_ws,
                        const float* __restrict__ Wx, const float* __restrict__ Wh,
                        float* __restrict__ gates_part) {
    __shared__ __attribute__((aligned(16))) float xt[64 * 64];
    int tid = threadIdx.x;
    int lane16 = tid & 15, rowg = tid >> 4;
    int s = blockIdx.x & 7, jt = blockIdx.x >> 3;
    int jb = jt * 64;
    float acc[4][4] = {};
    for (int ch = 0; ch < 3; ++ch) {
        int kbase = s * 192 + ch * 64;
        __syncthreads();
        for (int it = 0; it < 4; ++it) {
            int nrow = (tid >> 4) + it * 16;
            int k4 = tid & 15;
            int gk = kbase + k4 * 4;
            const float* src;
            if (gk < 512)       src = &z_ws[nrow * 512 + gk];
            else if (gk < 1024) src = &emb[(size_t)tok_ws[nrow] * 512 + (gk - 512)];
            else                src = &h_ws[nrow * 512 + (gk - 1024)];
            float4 v = *(const float4*)src;
            int col = (nrow + k4 * 4) & 63;
            xt[(k4 * 4 + 0) * 64 + col] = v.x;
            xt[(k4 * 4 + 1) * 64 + col] = v.y;
            xt[(k4 * 4 + 2) * 64 + col] = v.z;
            xt[(k4 * 4 + 3) * 64 + col] = v.w;
        }
        __syncthreads();
#pragma unroll 8
        for (int kk = 0; kk < 64; ++kk) {
            int gk = kbase + kk;
            const float* wrow = (gk < 1024) ? &Wx[(size_t)gk * G4] : &Wh[(size_t)(gk - 1024) * G4];
            float4 w4 = *(const float4*)&wrow[jb + lane16 * 4];
            float4 h4 = *(const float4*)&xt[kk * 64 + ((rowg * 4 + (kk & ~3)) & 63)];
            float hv[4] = {h4.x, h4.y, h4.z, h4.w};
            float wv[4] = {w4.x, w4.y, w4.z, w4.w};
#pragma unroll
            for (int r = 0; r < 4; ++r)
#pragma unroll
                for (int j = 0; j < 4; ++j) acc[r][j] = fmaf(hv[r], wv[j], acc[r][j]);
        }
    }
    float* gp = gates_part + (size_t)s * NB * G4;
    for (int r = 0; r < 4; ++r) {
        float4 o = {acc[r][0], acc[r][1], acc[r][2], acc[r][3]};
        *(float4*)&gp[(size_t)(rowg * 4 + r) * G4 + jb + lane16 * 4] = o;
    }
}

// ---------------- per step: reduce gate partials + LSTM cell + h bf16x3 split ----------------
__global__ void k_lstm(const float* __restrict__ gates_part, const float* __restrict__ b_lstm,
                       float* __restrict__ h_ws, float* __restrict__ c_ws,
                       unsigned short* __restrict__ h_hi, unsigned short* __restrict__ h_mid,
                       unsigned short* __restrict__ h_lo) {
    int idx = blockIdx.x * 256 + threadIdx.x;  // 0..32767 = n*512 + hh
    int n = idx >> 9, hh = idx & 511;
    float ig = b_lstm[hh], fg = b_lstm[512 + hh], gg = b_lstm[1024 + hh], og = b_lstm[1536 + hh];
    for (int s = 0; s < 8; ++s) {
        const float* gp = gates_part + (size_t)s * NB * G4 + (size_t)n * G4;
        ig += gp[hh]; fg += gp[512 + hh]; gg += gp[1024 + hh]; og += gp[1536 + hh];
    }
    float c = c_ws[idx];
    float cn = fast_sigmoid(fg) * c + fast_sigmoid(ig) * fast_tanh(gg);
    float hn = fast_sigmoid(og) * fast_tanh(cn);
    c_ws[idx] = cn;
    h_ws[idx] = hn;
    unsigned short a, b, cc;
    split3(hn, a, b, cc);
    h_hi[idx] = a; h_mid[idx] = b; h_lo[idx] = cc;   // [m][k] row-major, A-frag friendly
}

// ---------------- per step: logits = h @ Wout + bout via bf16x3 MFMA (pre-split W) ----------------
// Block: 64 vocab cols x 64 batch rows. 4 waves K-split (each K=128).
// A-frag: A[m=lane&15][k=quad*8+j] <- 16B from h_{hi,mid,lo}[m][k].
// B-frag: B[k=quad*8+j][n=lane&15] <- 16B from wt_*[n][k] (pre-split, transposed).
__global__ void k_logits(const unsigned short* __restrict__ h_hi,
                         const unsigned short* __restrict__ h_mid,
                         const unsigned short* __restrict__ h_lo,
                         const unsigned short* __restrict__ wt_hi,
                         const unsigned short* __restrict__ wt_mid,
                         const unsigned short* __restrict__ wt_lo,
                         const float* __restrict__ bout,
                         float* __restrict__ pval, int* __restrict__ pidx) {
    __shared__ __attribute__((aligned(16))) float part[4 * 64 * 64];  // 64 KB
    int tid = threadIdx.x;
    int w = tid >> 6, lane = tid & 63;
    int l15 = lane & 15, quad = lane >> 4;
    int jb = blockIdx.x * 64;
    if (jb > VD - 64) jb = VD - 64;   // clamp last tile; overlap recompute is harmless
    int kb = w * 128;

    float4v acc[4][4] = {{{0.f}}};    // [m-tile][n-tile]
    for (int c = 0; c < 4; ++c) {
        int k0 = kb + c * 32;
        short8v afrag[4][3];
#pragma unroll
        for (int mt = 0; mt < 4; ++mt) {
            size_t off = (size_t)(mt * 16 + l15) * 512 + k0 + quad * 8;
            afrag[mt][0] = *(const short8v*)&h_hi[off];
            afrag[mt][1] = *(const short8v*)&h_mid[off];
            afrag[mt][2] = *(const short8v*)&h_lo[off];
        }
#pragma unroll
        for (int nt = 0; nt < 4; ++nt) {
            size_t boff = (size_t)(jb + nt * 16 + l15) * 512 + k0 + quad * 8;
            short8v bhi  = *(const short8v*)&wt_hi[boff];
            short8v bmid = *(const short8v*)&wt_mid[boff];
            short8v blo  = *(const short8v*)&wt_lo[boff];
#pragma unroll
            for (int mt = 0; mt < 4; ++mt) {
                float4v a = acc[mt][nt];
                a = __builtin_amdgcn_mfma_f32_16x16x32_bf16(afrag[mt][2], bhi,  a, 0, 0, 0);
                a = __builtin_amdgcn_mfma_f32_16x16x32_bf16(afrag[mt][0], blo,  a, 0, 0, 0);
                a = __builtin_amdgcn_mfma_f32_16x16x32_bf16(afrag[mt][1], bmid, a, 0, 0, 0);
                a = __builtin_amdgcn_mfma_f32_16x16x32_bf16(afrag[mt][1], bhi,  a, 0, 0, 0);
                a = __builtin_amdgcn_mfma_f32_16x16x32_bf16(afrag[mt][0], bmid, a, 0, 0, 0);
                a = __builtin_amdgcn_mfma_f32_16x16x32_bf16(afrag[mt][0], bhi,  a, 0, 0, 0);
                acc[mt][nt] = a;
            }
        }
    }
    // write K-partials: part[w][m][n]
    float* myp = part + w * 4096;
#pragma unroll
    for (int mt = 0; mt < 4; ++mt)
#pragma unroll
        for (int nt = 0; nt < 4; ++nt)
#pragma unroll
            for (int r = 0; r < 4; ++r)
                myp[(mt * 16 + quad * 4 + r) * 64 + nt * 16 + l15] = acc[mt][nt][r];
    __syncthreads();
    // reduce 4 partials + bias + per-row argmax; thread -> (row = tid>>2, 16 cols)
    int row = tid >> 2, cg = (tid & 3) << 4;
    const float* p0 = part + row * 64 + cg;
    float best = -INFINITY;
    int bi = 0x7fffffff;
#pragma unroll
    for (int c4 = 0; c4 < 16; c4 += 4) {
        float4 s0 = *(const float4*)&p0[c4];
        float4 s1 = *(const float4*)&p0[4096 + c4];
        float4 s2 = *(const float4*)&p0[8192 + c4];
        float4 s3 = *(const float4*)&p0[12288 + c4];
        float4 b4 = *(const float4*)&bout[jb + cg + c4];
        float v0 = s0.x + s1.x + s2.x + s3.x + b4.x;
        float v1 = s0.y + s1.y + s2.y + s3.y + b4.y;
        float v2 = s0.z + s1.z + s2.z + s3.z + b4.z;
        float v3 = s0.w + s1.w + s2.w + s3.w + b4.w;
        int base = jb + cg + c4;
        if (v0 > best) { best = v0; bi = base; }
        if (v1 > best) { best = v1; bi = base + 1; }
        if (v2 > best) { best = v2; bi = base + 2; }
        if (v3 > best) { best = v3; bi = base + 3; }
    }
    for (int m = 1; m < 4; m <<= 1) {
        float ov = __shfl_xor(best, m, 64);
        int oi = __shfl_xor(bi, m, 64);
        if (ov > best || (ov == best && oi < bi)) { best = ov; bi = oi; }
    }
    if ((tid & 3) == 0) {
        pval[row * NB5 + blockIdx.x] = best;
        pidx[row * NB5 + blockIdx.x] = bi;
    }
}

// ---------------- per step: final argmax over block partials -> token ----------------
__global__ void k_argmax(const float* __restrict__ pval, const int* __restrict__ pidx,
                         int* __restrict__ tok_ws, int* __restrict__ out, int t) {
    int n = blockIdx.x, lane = threadIdx.x;
    float best = -INFINITY; int bi = 0x7fffffff;
    for (int b = lane; b < NB5; b += 64) {
        float v = pval[n * NB5 + b];
        int id = pidx[n * NB5 + b];
        if (v > best || (v == best && id < bi)) { best = v; bi = id; }
    }
    for (int m = 1; m < 64; m <<= 1) {
        float ov = __shfl_xor(best, m, 64);
        int oi = __shfl_xor(bi, m, 64);
        if (ov > best || (ov == best && oi < bi)) { best = ov; bi = oi; }
    }
    if (lane == 0) { tok_ws[n] = bi; out[n * TS + t] = bi; }
}

extern "C" void kernel_launch(void* const* d_in, const int* in_sizes, int n_in,
                              void* d_out, int out_size, void* d_ws, size_t ws_size,
                              hipStream_t stream) {
    const float* hl     = (const float*)d_in[0];
    const float* emb    = (const float*)d_in[1];
    const float* Wh0    = (const float*)d_in[2];
    const float* bh0    = (const float*)d_in[3];
    const float* Wc0    = (const float*)d_in[4];
    const float* bc0    = (const float*)d_in[5];
    const float* Wa     = (const float*)d_in[6];
    const float* Ua     = (const float*)d_in[7];
    const float* ba     = (const float*)d_in[8];
    const float* va     = (const float*)d_in[9];
    const float* Wb     = (const float*)d_in[10];
    const float* bb     = (const float*)d_in[11];
    const float* Wx     = (const float*)d_in[12];
    const float* Wh     = (const float*)d_in[13];
    const float* b_lstm = (const float*)d_in[14];
    const float* Wout   = (const float*)d_in[15];
    const float* bout   = (const float*)d_in[16];

    float* ws         = (float*)d_ws;
    float* hlwa       = ws;                          // 6422528
    float* h_ws       = ws + 6422528;                // 32768
    float* c_ws       = h_ws + 32768;                // 32768
    float* z_ws       = c_ws + 32768;                // 32768
    float* e_ws       = z_ws + 32768;                // 12544
    int*   tok_ws     = (int*)(e_ws + 12544);        // 64
    float* hua_part   = e_ws + 12544 + 64;           // 8*64*512 = 262144
    float* gates_part = hua_part + 262144;           // 8*64*2048 = 1048576
    float* pval       = gates_part + 1048576;        // 30016
    int*   pidx       = (int*)(pval + 30016);        // 30016
    unsigned short* h_hi  = (unsigned short*)(pidx + 30016);  // 32768 ushort each
    unsigned short* h_mid = h_hi + 32768;
    unsigned short* h_lo  = h_mid + 32768;
    unsigned short* wt_hi  = h_lo + 32768;           // 30016*512 ushort each (~30.7MB)
    unsigned short* wt_mid = wt_hi + (size_t)VDP * 512;
    unsigned short* wt_lo  = wt_mid + (size_t)VDP * 512;
    int*   out        = (int*)d_out;

    k_init<<<64, 256, 0, stream>>>(hl, Wh0, bh0, Wc0, bc0, h_ws, c_ws, tok_ws);
    k_wsplit<<<dim3(NB5, 8), 256, 0, stream>>>(Wout, wt_hi, wt_mid, wt_lo);
    k_hlwa<<<dim3(196, 8), 256, 0, stream>>>(hl, Wa, hlwa);
    for (int t = 0; t < TS; ++t) {
        k_hua<<<64, 256, 0, stream>>>(h_ws, Ua, hua_part);
        k_att_e<<<256, 256, 0, stream>>>(hlwa, hua_part, ba, va, e_ws);
        k_soft_z<<<256, 256, 0, stream>>>(e_ws, hl, h_ws, Wb, bb, z_ws);
        k_gates<<<256, 256, 0, stream>>>(z_ws, emb, tok_ws, h_ws, Wx, Wh, gates_part);
        k_lstm<<<128, 256, 0, stream>>>(gates_part, b_lstm, h_ws, c_ws, h_hi, h_mid, h_lo);
        k_logits<<<NB5, 256, 0, stream>>>(h_hi, h_mid, h_lo, wt_hi, wt_mid, wt_lo,
                                          bout, pval, pidx);
        k_argmax<<<64, 64, 0, stream>>>(pval, pidx, tok_ws, out, t);
    }
}